// Round 8
// baseline (278.121 us; speedup 1.0000x reference)
//
#include <hip/hip_runtime.h>
#include <hip/hip_bf16.h>
#include <stdint.h>

#define BATCH   4096
#define IN_DIM  1024
#define OUT_DIM 1024
#define GRID_G  8
#define K8      16384            // spline K: 16 planes (8 cos + 8 sin) * 1024
#define KB      1024             // base K (silu plane)
#define SPLIT8  4                // spline split-K: 32 iters of BK=128 bytes
#define WSCALE  256.0f           // spline weights scaled into e4m3 range

typedef __bf16 bf16x8 __attribute__((ext_vector_type(8)));
typedef float  f32x4  __attribute__((ext_vector_type(4)));
typedef int    i32x4  __attribute__((ext_vector_type(4)));
typedef int    i32x8  __attribute__((ext_vector_type(8)));

// pack 8 floats -> 8 fp8 e4m3 bytes (HW cvt), little-endian k-order
__device__ inline void store_fp8x8(void* p, const float v[8]) {
    int lo = 0, hi = 0;
    lo = __builtin_amdgcn_cvt_pk_fp8_f32(v[0], v[1], lo, false);
    lo = __builtin_amdgcn_cvt_pk_fp8_f32(v[2], v[3], lo, true);
    hi = __builtin_amdgcn_cvt_pk_fp8_f32(v[4], v[5], hi, false);
    hi = __builtin_amdgcn_cvt_pk_fp8_f32(v[6], v[7], hi, true);
    *(int2*)p = make_int2(lo, hi);
}

// ---------------------------------------------------------------------------
// Prep (merged): blocks [0,2048) build features; [2048,2560) fold weights.
// Spline planes (fp8): A8[b, p*1024+i], p=0..7 cos(g=p+1), p=8..15 sin(g=p-7).
// Base plane (bf16):   Ab[b,i] = silu(x);  Wb[o,i] = scale_base.
// W8[o, p*1024+i] = ss*coeff*WSCALE (fp8).
// sin/cos via RAW HW ops (v_sin_f32/v_cos_f32, input in REVOLUTIONS,
// fract-reduced) — __sincosf's pointer-output libm path was ~110 us of
// unexplained prep time (suspected scratch round-trip per call).
// ---------------------------------------------------------------------------
__global__ void prep(const float* __restrict__ x, const float* __restrict__ sb,
                     const float* __restrict__ ss, const float* __restrict__ coeff,
                     uint8_t* __restrict__ A8, uint8_t* __restrict__ W8,
                     __bf16* __restrict__ Ab, __bf16* __restrict__ Wb) {
    if (blockIdx.x < 2048) {
        int t  = blockIdx.x * blockDim.x + threadIdx.x;   // over BATCH*IN_DIM/8
        int b  = t >> 7;
        int i0 = (t & 127) * 8;
        const float4* xp = (const float4*)(x + (size_t)b * IN_DIM + i0);
        float4 x0 = xp[0], x1 = xp[1];
        float xv[8] = {x0.x, x0.y, x0.z, x0.w, x1.x, x1.y, x1.z, x1.w};

        constexpr float INV2PI = 0.15915494309189535f;
        float c1[8], s1[8], ck[8], sk[8];
        bf16x8 v;
#pragma unroll
        for (int j = 0; j < 8; ++j) {
            float xx  = xv[j];
            float sil = xx / (1.f + __expf(-xx));
            v[j] = (__bf16)sil;
            float rev = xx * INV2PI;
            rev -= floorf(rev);                    // [0,1) revolutions
            s1[j] = __builtin_amdgcn_sinf(rev);    // v_sin_f32: sin(2*pi*rev)
            c1[j] = __builtin_amdgcn_cosf(rev);    // v_cos_f32
            ck[j] = c1[j]; sk[j] = s1[j];
        }
        *(bf16x8*)(Ab + (size_t)b * IN_DIM + i0) = v;

        uint8_t* a8 = A8 + (size_t)b * K8 + i0;
#pragma unroll
        for (int g = 1; g <= GRID_G; ++g) {
            float vc[8], vs[8];
#pragma unroll
            for (int j = 0; j < 8; ++j) {
                vc[j] = ck[j];
                vs[j] = sk[j];
                float cn = ck[j] * c1[j] - sk[j] * s1[j];
                float sn = sk[j] * c1[j] + ck[j] * s1[j];
                ck[j] = cn; sk[j] = sn;
            }
            store_fp8x8(a8 + (size_t)(g - 1) * IN_DIM, vc);
            store_fp8x8(a8 + (size_t)(GRID_G + g - 1) * IN_DIM, vs);
        }
    } else {
        int t  = (blockIdx.x - 2048) * blockDim.x + threadIdx.x; // over OUT_DIM*IN_DIM/8
        int o  = t >> 7;
        int i0 = (t & 127) * 8;
        size_t oi = (size_t)o * IN_DIM + i0;

        float s[8];
        {
            const float4* sp = (const float4*)(ss + oi);
            float4 s0 = sp[0], s1v = sp[1];
            s[0]=s0.x; s[1]=s0.y; s[2]=s0.z; s[3]=s0.w;
            s[4]=s1v.x; s[5]=s1v.y; s[6]=s1v.z; s[7]=s1v.w;
        }
        {
            const float4* bp = (const float4*)(sb + oi);
            float4 b0 = bp[0], b1 = bp[1];
            float bv[8] = {b0.x, b0.y, b0.z, b0.w, b1.x, b1.y, b1.z, b1.w};
            bf16x8 v;
#pragma unroll
            for (int j = 0; j < 8; ++j) v[j] = (__bf16)bv[j];
            *(bf16x8*)(Wb + oi) = v;
        }
        uint8_t* w8 = W8 + (size_t)o * K8 + i0;
#pragma unroll
        for (int p = 0; p < 2; ++p) {
            const float* cp = coeff + ((size_t)p * OUT_DIM * IN_DIM + oi) * GRID_G;
            float c[8][8];                     // [j][g]
#pragma unroll
            for (int j = 0; j < 8; ++j) {
                const float4* cj = (const float4*)(cp + (size_t)j * GRID_G);
                float4 a0 = cj[0], a1 = cj[1];
                c[j][0]=a0.x; c[j][1]=a0.y; c[j][2]=a0.z; c[j][3]=a0.w;
                c[j][4]=a1.x; c[j][5]=a1.y; c[j][6]=a1.z; c[j][7]=a1.w;
            }
#pragma unroll
            for (int g = 0; g < GRID_G; ++g) {
                float v[8];
#pragma unroll
                for (int j = 0; j < 8; ++j) v[j] = s[j] * c[j][g] * WSCALE;
                store_fp8x8(w8 + (size_t)(p * GRID_G + g) * IN_DIM, v);
            }
        }
    }
}

// ---------------------------------------------------------------------------
// Unified GEMM. Grid (8, 32, 5):
//   z in [0,4): spline fp8, MX-scaled mfma 16x16x128 (unit scales), split-K x4,
//               BK=128 bytes, 32 iters/block.
//   z == 4:     base bf16, mfma 16x16x32, full K=1024, 16 iters of 64 elems.
// Both: 128x128 tile, 4 waves 2x2, 32 KB LDS (4 blocks/CU), XOR 16B-chunk
// swizzle (c ^ (row&7)) on staging global addr. Epilogue: HW f32 atomic add.
// ---------------------------------------------------------------------------
__global__ __launch_bounds__(256, 4) void gemm_all(const uint8_t* __restrict__ A8,
                                                   const uint8_t* __restrict__ W8,
                                                   const uint8_t* __restrict__ Ab,
                                                   const uint8_t* __restrict__ Wb,
                                                   float* __restrict__ C) {
    __shared__ __align__(16) uint8_t As[16384];
    __shared__ __align__(16) uint8_t Bs[16384];
    const int tid = threadIdx.x;
    const int w   = tid >> 6;
    const int l   = tid & 63;
    const int bn  = blockIdx.x;    // N/128 = 8
    const int bm  = blockIdx.y;    // M/128 = 32
    const int kz  = blockIdx.z;    // 0..3 spline chunks, 4 = base
    const int wm  = w & 1;
    const int wn  = w >> 1;

    f32x4 acc[4][4] = {};

    const int srow   = l >> 3;                  // 0..7
    const int schunk = ((l & 7) ^ srow) * 16;   // byte offset of swizzled 16B chunk
    const int lm = l & 15;
    const int q  = l >> 4;                      // 0..3
    float oscale;

    if (kz < SPLIT8) {
        // ---------------- spline fp8 path ----------------
        const uint8_t* Ag = A8 + (size_t)(bm * 128 + w * 32 + srow) * K8 + kz * (K8 / SPLIT8) + schunk;
        const uint8_t* Bg = W8 + (size_t)(bn * 128 + w * 32 + srow) * K8 + kz * (K8 / SPLIT8) + schunk;
        const int c0 = (q * 2) << 4, c1 = (q * 2 + 1) << 4;   // lane's two chunk offsets

        for (int ks = 0; ks < (K8 / SPLIT8) / 128; ++ks) {
#pragma unroll
            for (int j = 0; j < 4; ++j) {
                __builtin_amdgcn_global_load_lds(
                    (const uint32_t*)(Ag + (size_t)(j * 8) * K8),
                    (uint32_t*)(As + (w * 32 + j * 8) * 128), 16, 0, 0);
                __builtin_amdgcn_global_load_lds(
                    (const uint32_t*)(Bg + (size_t)(j * 8) * K8),
                    (uint32_t*)(Bs + (w * 32 + j * 8) * 128), 16, 0, 0);
            }
            Ag += 128; Bg += 128;
            __syncthreads();

            i32x8 bf[4];
#pragma unroll
            for (int j = 0; j < 4; ++j) {
                const int row = wn * 64 + j * 16 + lm;
                const int sw  = (row & 7) << 4;
                const uint8_t* rp = Bs + row * 128;
                i32x4 lo = *(const i32x4*)(rp + (c0 ^ sw));
                i32x4 hi = *(const i32x4*)(rp + (c1 ^ sw));
                bf[j] = __builtin_shufflevector(lo, hi, 0, 1, 2, 3, 4, 5, 6, 7);
            }
#pragma unroll
            for (int i = 0; i < 4; ++i) {
                const int row = wm * 64 + i * 16 + lm;
                const int sw  = (row & 7) << 4;
                const uint8_t* rp = As + row * 128;
                i32x4 lo = *(const i32x4*)(rp + (c0 ^ sw));
                i32x4 hi = *(const i32x4*)(rp + (c1 ^ sw));
                i32x8 af = __builtin_shufflevector(lo, hi, 0, 1, 2, 3, 4, 5, 6, 7);
#pragma unroll
                for (int j = 0; j < 4; ++j)
                    acc[i][j] = __builtin_amdgcn_mfma_scale_f32_16x16x128_f8f6f4(
                        af, bf[j], acc[i][j], 0, 0, 0, 0x7f7f7f7f, 0, 0x7f7f7f7f);
            }
            __syncthreads();
        }
        oscale = 1.0f / WSCALE;
    } else {
        // ---------------- base bf16 path (full K, no split) ----------------
        const uint8_t* Ag = Ab + (size_t)(bm * 128 + w * 32 + srow) * (KB * 2) + schunk;
        const uint8_t* Bg = Wb + (size_t)(bn * 128 + w * 32 + srow) * (KB * 2) + schunk;

        for (int ks = 0; ks < (KB * 2) / 128; ++ks) {
#pragma unroll
            for (int j = 0; j < 4; ++j) {
                __builtin_amdgcn_global_load_lds(
                    (const uint32_t*)(Ag + (size_t)(j * 8) * (KB * 2)),
                    (uint32_t*)(As + (w * 32 + j * 8) * 128), 16, 0, 0);
                __builtin_amdgcn_global_load_lds(
                    (const uint32_t*)(Bg + (size_t)(j * 8) * (KB * 2)),
                    (uint32_t*)(Bs + (w * 32 + j * 8) * 128), 16, 0, 0);
            }
            Ag += 128; Bg += 128;
            __syncthreads();

#pragma unroll
            for (int h = 0; h < 2; ++h) {
                bf16x8 af[4], bfr[4];
#pragma unroll
                for (int i = 0; i < 4; ++i) {
                    const int row = wm * 64 + i * 16 + lm;
                    af[i] = *(const bf16x8*)(As + row * 128 + ((((h * 4 + q) ^ (row & 7))) << 4));
                }
#pragma unroll
                for (int j = 0; j < 4; ++j) {
                    const int row = wn * 64 + j * 16 + lm;
                    bfr[j] = *(const bf16x8*)(Bs + row * 128 + ((((h * 4 + q) ^ (row & 7))) << 4));
                }
#pragma unroll
                for (int i = 0; i < 4; ++i)
#pragma unroll
                    for (int j = 0; j < 4; ++j)
                        acc[i][j] = __builtin_amdgcn_mfma_f32_16x16x32_bf16(af[i], bfr[j], acc[i][j], 0, 0, 0);
            }
            __syncthreads();
        }
        oscale = 1.0f;
    }

    // epilogue: C/D layout col = lane&15, row = (lane>>4)*4 + reg
    const int row0 = bm * 128 + wm * 64 + q * 4;
    const int col0 = bn * 128 + wn * 64 + lm;
#pragma unroll
    for (int i = 0; i < 4; ++i)
#pragma unroll
        for (int j = 0; j < 4; ++j)
#pragma unroll
            for (int r = 0; r < 4; ++r)
                unsafeAtomicAdd(&C[(size_t)(row0 + i * 16 + r) * OUT_DIM + col0 + j * 16],
                                acc[i][j][r] * oscale);
}

// ---------------------------------------------------------------------------
extern "C" void kernel_launch(void* const* d_in, const int* in_sizes, int n_in,
                              void* d_out, int out_size, void* d_ws, size_t ws_size,
                              hipStream_t stream) {
    const float* x     = (const float*)d_in[0];   // (B, I)
    const float* sb    = (const float*)d_in[1];   // (O, I)
    const float* ss    = (const float*)d_in[2];   // (O, I)
    const float* coeff = (const float*)d_in[3];   // (2, O, I, G)
    float* out = (float*)d_out;                   // (B, O)

    uint8_t* A8 = (uint8_t*)d_ws;                          // 4096*16384 fp8 = 67.1 MB
    uint8_t* W8 = A8 + (size_t)BATCH * K8;                 // 1024*16384 fp8 = 16.8 MB
    __bf16*  Ab = (__bf16*)(W8 + (size_t)OUT_DIM * K8);    // 4096*1024 bf16 = 8.4 MB
    __bf16*  Wb = Ab + (size_t)BATCH * KB;                 // 1024*1024 bf16 = 2.1 MB

    hipLaunchKernelGGL(prep, dim3(2048 + 512), dim3(256), 0, stream,
                       x, sb, ss, coeff, A8, W8, Ab, Wb);
    hipMemsetAsync(out, 0, (size_t)BATCH * OUT_DIM * sizeof(float), stream);
    hipLaunchKernelGGL(gemm_all, dim3(OUT_DIM / 128, BATCH / 128, SPLIT8 + 1), dim3(256), 0, stream,
                       A8, W8, (const uint8_t*)Ab, (const uint8_t*)Wb, out);
}